// Round 13
// baseline (674.856 us; speedup 1.0000x reference)
//
#include <hip/hip_runtime.h>
#include <hip/hip_bf16.h>

#define NN 50000
#define EE 600000
#define SREP 64   // stats replicas (atomic decontention)
#define SCB 49    // scan blocks: 49 x 1024 elems >= NN

#if __has_builtin(__builtin_amdgcn_global_atomic_fadd_v2bf16)
#define USE_PK 1
typedef short bf2v __attribute__((ext_vector_type(2)));
#else
#define USE_PK 0
#endif

typedef short bf16x8 __attribute__((ext_vector_type(8)));
typedef float f32x4 __attribute__((ext_vector_type(4)));

__device__ inline ushort f2bf(float x) {  // round-to-nearest-even bf16
  unsigned u = __float_as_uint(x);
  u = (u + 0x7fffu + ((u >> 16) & 1u)) >> 16;
  return (ushort)u;
}
__device__ inline float bflo(uint t) { return __uint_as_float(t << 16); }
__device__ inline float bfhi(uint t) { return __uint_as_float(t & 0xffff0000u); }
__device__ inline uint f22bf(float a, float b) { return ((uint)f2bf(b) << 16) | (uint)f2bf(a); }

// ---------- graph preprocessing ----------
__global__ void count2_k(const int* __restrict__ ei, int* __restrict__ cnt_s,
                         int* __restrict__ cnt_d) {
  int e = blockIdx.x * 256 + threadIdx.x;
  if (e < EE) {
    atomicAdd(&cnt_s[ei[e]], 1);
    atomicAdd(&cnt_d[ei[EE + e]], 1);
  }
}

__global__ __launch_bounds__(256) void scanA_k(const int* __restrict__ cnt,
                                               int* __restrict__ cur,
                                               int* __restrict__ bsum) {
  __shared__ int ls[256];
  const int t = threadIdx.x;
  const int base = blockIdx.x * 1024 + t * 4;
  int4 v = {0, 0, 0, 0};
  if (base + 3 < NN) v = *(const int4*)(cnt + base);
  else {
    if (base + 0 < NN) v.x = cnt[base + 0];
    if (base + 1 < NN) v.y = cnt[base + 1];
    if (base + 2 < NN) v.z = cnt[base + 2];
  }
  ls[t] = v.x + v.y + v.z + v.w;
  __syncthreads();
  for (int off = 1; off < 256; off <<= 1) {
    int u = (t >= off) ? ls[t - off] : 0;
    __syncthreads();
    ls[t] += u;
    __syncthreads();
  }
  int ex = (t == 0) ? 0 : ls[t - 1];
  int4 o;
  o.x = ex;
  o.y = ex + v.x;
  o.z = o.y + v.y;
  o.w = o.z + v.z;
  if (base + 3 < NN) *(int4*)(cur + base) = o;
  else {
    if (base + 0 < NN) cur[base + 0] = o.x;
    if (base + 1 < NN) cur[base + 1] = o.y;
    if (base + 2 < NN) cur[base + 2] = o.z;
  }
  if (t == 255) bsum[blockIdx.x] = ls[255];
}

__global__ __launch_bounds__(64) void scanB_k(int* __restrict__ bsum) {
  int t = threadIdx.x;
  int own = (t < SCB) ? bsum[t] : 0;
  int v = own;
#pragma unroll
  for (int off = 1; off < 64; off <<= 1) {
    int u = __shfl_up(v, off, 64);
    if (t >= off) v += u;
  }
  if (t < SCB) bsum[t] = v - own;
}

__global__ __launch_bounds__(256) void scanC_k(int* __restrict__ cur,
                                               const int* __restrict__ bsum,
                                               const int* __restrict__ cnt_d,
                                               float* __restrict__ invd) {
  const int t = threadIdx.x;
  const int base = blockIdx.x * 1024 + t * 4;
  const int off = bsum[blockIdx.x];
  if (base + 3 < NN) {
    int4 v = *(int4*)(cur + base);
    v.x += off; v.y += off; v.z += off; v.w += off;
    *(int4*)(cur + base) = v;
    int4 cd = *(const int4*)(cnt_d + base);
    float4 iv;
    iv.x = 1.0f / (float)max(cd.x, 1);
    iv.y = 1.0f / (float)max(cd.y, 1);
    iv.z = 1.0f / (float)max(cd.z, 1);
    iv.w = 1.0f / (float)max(cd.w, 1);
    *(float4*)(invd + base) = iv;
  } else {
    for (int i = 0; i < 4; ++i) {
      if (base + i < NN) {
        cur[base + i] += off;
        invd[base + i] = 1.0f / (float)max(cnt_d[base + i], 1);
      }
    }
  }
}

__global__ void fill_csc_k(const int* __restrict__ ei, const float* __restrict__ ew,
                           int* __restrict__ cur_s, int4* __restrict__ e4) {
  int e = blockIdx.x * 256 + threadIdx.x;
  if (e < EE) {
    int s = ei[e], d = ei[EE + e];
    int pc = atomicAdd(&cur_s[s], 1);
    int4 v;
    v.x = s; v.y = d; v.z = __float_as_int(ew[e]); v.w = 0;
    e4[pc] = v;
  }
}

// ---------- weight precompute: all 6 W matrices -> bf16 swizzled image ----
__global__ void wpk_k(const float* __restrict__ Wl0, const float* __restrict__ Wr0,
                      const float* __restrict__ Wl1, const float* __restrict__ Wr1,
                      const float* __restrict__ Wl2, const float* __restrict__ Wr2,
                      ushort* __restrict__ wbuf) {
  int idx = blockIdx.x * 256 + threadIdx.x;  // 0..81919
  const float* W; int F, r, off;
  if (idx < 16384)      { W = Wl0; F = 128; r = idx;         off = 0; }
  else if (idx < 32768) { W = Wr0; F = 128; r = idx - 16384; off = 16384; }
  else if (idx < 49152) { W = Wl1; F = 128; r = idx - 32768; off = 32768; }
  else if (idx < 65536) { W = Wr1; F = 128; r = idx - 49152; off = 49152; }
  else if (idx < 73728) { W = Wl2; F = 64;  r = idx - 65536; off = 65536; }
  else                  { W = Wr2; F = 64;  r = idx - 73728; off = 73728; }
  int k = r / F, n = r % F;
  wbuf[off + n * 128 + ((((k >> 3) + n) & 15) << 3) + (k & 7)] = f2bf(W[k * F + n]);
}

// ---- shared device helpers for the two MFMA kernels ----
// BN scale/shift from SREP-replicated stats (inline bn_fin)
__device__ inline void bn_reduce(const float* statsbIn, const float* gamma,
                                 const float* beta, float* ssL, int tid) {
  if (tid < 128) {
    float sum = 0.f, sq = 0.f;
#pragma unroll 8
    for (int r = 0; r < SREP; ++r) {
      sum += statsbIn[r * 256 + tid];
      sq  += statsbIn[r * 256 + 128 + tid];
    }
    float mu = sum * (1.0f / (float)NN);
    float var = sq * (1.0f / (float)NN) - mu * mu;
    float sc = gamma[tid] * rsqrtf(var + 1e-5f);
    ssL[tid] = sc;
    ssL[128 + tid] = beta[tid] - mu * sc;
  }
}

// stage 64-node H tile into swizzled bf16 LDS (optionally bn+relu)
template <bool HAS_BN, bool HB16>
__device__ inline void stage_h(const void* H, ushort* Hs, const float* ssL,
                               int nb, int tid) {
  if (HB16) {
    for (int i = tid; i < 64 * 16; i += 256) {
      int m = i >> 4, c = i & 15;
      int node = nb + m;
      uint4 hv = {0, 0, 0, 0};
      if (node < NN) hv = ((const uint4*)H)[(size_t)node * 16 + c];
      if (HAS_BN) {
        int gk = c * 8;
        uint* p = (uint*)&hv;
#pragma unroll
        for (int j = 0; j < 4; ++j) {
          float f0 = fmaxf(fmaf(bflo(p[j]), ssL[gk + 2 * j], ssL[128 + gk + 2 * j]), 0.f);
          float f1 = fmaxf(fmaf(bfhi(p[j]), ssL[gk + 2 * j + 1], ssL[128 + gk + 2 * j + 1]), 0.f);
          p[j] = f22bf(f0, f1);
        }
      }
      *(uint4*)&Hs[m * 128 + (((c + m) & 15) << 3)] = hv;
    }
  } else {
    for (int i = tid; i < 64 * 32; i += 256) {
      int m = i >> 5, kq = i & 31;
      int node = nb + m;
      float4 hv = {0.f, 0.f, 0.f, 0.f};
      if (node < NN) hv = ((const float4*)H)[(size_t)node * 32 + kq];
      if (HAS_BN) {
        int gk = kq * 4;
        hv.x = fmaxf(fmaf(hv.x, ssL[gk + 0], ssL[128 + gk + 0]), 0.f);
        hv.y = fmaxf(fmaf(hv.y, ssL[gk + 1], ssL[128 + gk + 1]), 0.f);
        hv.z = fmaxf(fmaf(hv.z, ssL[gk + 2], ssL[128 + gk + 2]), 0.f);
        hv.w = fmaxf(fmaf(hv.w, ssL[gk + 3], ssL[128 + gk + 3]), 0.f);
      }
      int c = kq >> 1;
      int base = m * 128 + (((c + m) & 15) << 3) + (kq & 1) * 4;
      ushort4 u4 = {f2bf(hv.x), f2bf(hv.y), f2bf(hv.z), f2bf(hv.w)};
      *(ushort4*)&Hs[base] = u4;
    }
  }
}

// ---------- gemm_tl: Tlb(chunked bf16) = bnrelu(H) @ Wl ----------
template <int F, bool HAS_BN, bool HB16>
__global__ __launch_bounds__(256) void gemm_tl(
    const void* __restrict__ H, const ushort* __restrict__ Wpre,
    const float* __restrict__ statsbIn, const float* __restrict__ gamma,
    const float* __restrict__ beta, ushort* __restrict__ Tlb) {
  __shared__ __align__(16) ushort Wt[F * 128];
  __shared__ __align__(16) ushort Hs[64 * 128];
  __shared__ float ssL[256];
  const int tid = threadIdx.x;
  const int nb = blockIdx.x * 64;
  if (HAS_BN) {
    bn_reduce(statsbIn, gamma, beta, ssL, tid);
    __syncthreads();
  }
  stage_h<HAS_BN, HB16>(H, Hs, ssL, nb, tid);
  __syncthreads();

  const int lane = tid & 63;
  const int w = tid >> 6;
  const int col = lane & 15;
  const int quad = lane >> 4;
  const int m = w * 16 + col;
  bf16x8 afrag[4];
#pragma unroll
  for (int s = 0; s < 4; ++s) {
    int c = s * 4 + quad;
    afrag[s] = *(const bf16x8*)&Hs[m * 128 + (((c + m) & 15) << 3)];
  }
  for (int i = tid; i < F * 16; i += 256) ((uint4*)Wt)[i] = ((const uint4*)Wpre)[i];
  __syncthreads();
#pragma unroll 2
  for (int ct = 0; ct < F / 16; ++ct) {
    int n = ct * 16 + col;
    f32x4 acc = {0.f, 0.f, 0.f, 0.f};
#pragma unroll
    for (int s = 0; s < 4; ++s) {
      int c = s * 4 + quad;
      bf16x8 b = *(const bf16x8*)&Wt[n * 128 + (((c + n) & 15) << 3)];
      acc = __builtin_amdgcn_mfma_f32_16x16x32_bf16(afrag[s], b, acc, 0, 0, 0);
    }
    int nodeb = nb + w * 16 + quad * 4;
#pragma unroll
    for (int r = 0; r < 4; ++r) {
      int node = nodeb + r;
      if (node < NN) {
        int cc = ct * 16 + col;
        Tlb[(size_t)(cc >> 5) * NN * 32 + (size_t)node * 32 + (cc & 31)] = f2bf(acc[r]);
      }
    }
  }
}

// ---------- edge-parallel aggregation via HW pk-bf16 atomics (at roofline) ----
template <int F>
__global__ __launch_bounds__(256, 8) void edge_atomic(
    const ushort* __restrict__ Tlb, const int4* __restrict__ e4,
    void* __restrict__ agg) {
  constexpr int L = F / 2;
  int gid = blockIdx.x * 256 + threadIdx.x;
  int e = gid / L;
  int cp = gid % L;
  if (e >= EE) return;
  int4 p = e4[e];
  float w = __int_as_float(p.z);
  int chunk = cp >> 4, coff = cp & 15;
  uint t = ((const uint*)Tlb)[(size_t)chunk * NN * 16 + (size_t)p.x * 16 + coff];
  float f0 = w * bflo(t);
  float f1 = w * bfhi(t);
#if USE_PK
  bf2v v;
  v.x = (short)f2bf(f0);
  v.y = (short)f2bf(f1);
  __builtin_amdgcn_global_atomic_fadd_v2bf16((bf2v*)((char*)agg + ((size_t)p.y * L + cp) * 4), v);
#else
  float* a = (float*)agg + ((size_t)p.y * L + cp) * 2;
  atomicAdd(a, f0);
  atomicAdd(a + 1, f1);
#endif
}

// ---------- combine_gemm: Tr-GEMM fused with combine ----------
// out[n][cc] = agg[n][cc]*invd[n] + (bnrelu(H)@Wr)[n][cc] + bias[cc]
template <int F, bool HAS_BN, bool HB16, bool STATS, bool ZERO, bool OUTF32>
__global__ __launch_bounds__(256) void combine_gemm(
    const void* __restrict__ H, const ushort* __restrict__ Wpre,
    const float* __restrict__ statsbIn, const float* __restrict__ gamma,
    const float* __restrict__ beta, void* __restrict__ agg,
    const float* __restrict__ invd, const float* __restrict__ bias,
    void* __restrict__ outp, float* __restrict__ statsbOut) {
  __shared__ __align__(16) ushort Wt[F * 128];
  __shared__ __align__(16) ushort Hs[64 * 128];
  __shared__ float ssL[256];
  __shared__ float ldsS[128], ldsQ[128];
  const int tid = threadIdx.x;
  const int nb = blockIdx.x * 64;
  if (HAS_BN) bn_reduce(statsbIn, gamma, beta, ssL, tid);
  if (STATS && tid < 128) { ldsS[tid] = 0.f; ldsQ[tid] = 0.f; }
  __syncthreads();
  stage_h<HAS_BN, HB16>(H, Hs, ssL, nb, tid);
  __syncthreads();

  const int lane = tid & 63;
  const int w = tid >> 6;
  const int col = lane & 15;
  const int quad = lane >> 4;
  const int m = w * 16 + col;
  bf16x8 afrag[4];
#pragma unroll
  for (int s = 0; s < 4; ++s) {
    int c = s * 4 + quad;
    afrag[s] = *(const bf16x8*)&Hs[m * 128 + (((c + m) & 15) << 3)];
  }
  for (int i = tid; i < F * 16; i += 256) ((uint4*)Wt)[i] = ((const uint4*)Wpre)[i];
  __syncthreads();

  constexpr int L = F / 2;
  uint* aggu = (uint*)agg;
#pragma unroll 2
  for (int ct = 0; ct < F / 16; ++ct) {
    int n = ct * 16 + col;
    f32x4 acc = {0.f, 0.f, 0.f, 0.f};
#pragma unroll
    for (int s = 0; s < 4; ++s) {
      int c = s * 4 + quad;
      bf16x8 b = *(const bf16x8*)&Wt[n * 128 + (((c + n) & 15) << 3)];
      acc = __builtin_amdgcn_mfma_f32_16x16x32_bf16(afrag[s], b, acc, 0, 0, 0);
    }
    const int cc = ct * 16 + col;
    const float bval = bias[cc];
    float Sl = 0.f, Ql = 0.f;
    int nodeb = nb + w * 16 + quad * 4;
#pragma unroll
    for (int r = 0; r < 4; ++r) {
      int node = nodeb + r;
      if (node < NN) {
        size_t ai = (size_t)node * L + (cc >> 1);
#if USE_PK
        uint a = aggu[ai];
        float av = (cc & 1) ? bfhi(a) : bflo(a);
        if (ZERO && (cc & 1) == 0) aggu[ai] = 0;
#else
        float av = ((float*)agg)[2 * ai + (cc & 1)];
        if (ZERO) ((float*)agg)[2 * ai + (cc & 1)] = 0.f;
#endif
        float v = fmaf(av, invd[node], acc[r] + bval);
        if (OUTF32) ((float*)outp)[(size_t)node * F + cc] = v;
        else ((ushort*)outp)[(size_t)node * 128 + cc] = f2bf(v);
        if (STATS) { Sl += v; Ql += v * v; }
      }
    }
    if (STATS) {
      atomicAdd(&ldsS[cc], Sl);
      atomicAdd(&ldsQ[cc], Ql);
    }
  }
  if (STATS) {
    __syncthreads();
    if (tid < 128) {
      float* sb = statsbOut + (size_t)(blockIdx.x & (SREP - 1)) * 256;
      atomicAdd(&sb[tid], ldsS[tid]);
      atomicAdd(&sb[128 + tid], ldsQ[tid]);
    }
  }
}

extern "C" void kernel_launch(void* const* d_in, const int* in_sizes, int n_in,
                              void* d_out, int out_size, void* d_ws, size_t ws_size,
                              hipStream_t stream) {
  (void)in_sizes; (void)n_in; (void)out_size; (void)ws_size;
  const float* x   = (const float*)d_in[0];
  const int*   ei  = (const int*)d_in[1];
  const float* ew  = (const float*)d_in[2];
  const float* Wl0 = (const float*)d_in[3];
  const float* Wr0 = (const float*)d_in[4];
  const float* b0  = (const float*)d_in[5];
  const float* Wl1 = (const float*)d_in[6];
  const float* Wr1 = (const float*)d_in[7];
  const float* b1  = (const float*)d_in[8];
  const float* Wl2 = (const float*)d_in[9];
  const float* Wr2 = (const float*)d_in[10];
  const float* b2  = (const float*)d_in[11];
  const float* g0  = (const float*)d_in[12];
  const float* be0 = (const float*)d_in[13];
  const float* g1  = (const float*)d_in[14];
  const float* be1 = (const float*)d_in[15];
  float* out = (float*)d_out;

  size_t off = 0;
  auto alloc = [&](size_t b) -> void* {
    void* p = (char*)d_ws + off;
    off += (b + 255) & ~(size_t)255;
    return p;
  };
  ushort* tlb   = (ushort*)alloc((size_t)NN * 128 * 2);  // 12.8 MB
  ushort* hpreA = (ushort*)alloc((size_t)NN * 128 * 2);  // 12.8 MB
  ushort* hpreB = (ushort*)alloc((size_t)NN * 128 * 2);  // 12.8 MB
#if USE_PK
  const size_t AGG_B = (size_t)NN * 128 * 2;
#else
  const size_t AGG_B = (size_t)NN * 128 * 4;
#endif
  void* agg    = alloc((size_t)NN * 128 * 4);            // 25.6 MB
  int4* e4     = (int4*)alloc((size_t)EE * 16);          // 9.6 MB
  ushort* wbuf = (ushort*)alloc(81920 * 2);
  int*  cnts   = (int*)alloc((size_t)NN * 2 * 4);
  int*  cnt_s  = cnts;
  int*  cnt_d  = cnts + NN;
  int*  cur_s  = (int*)alloc((size_t)NN * 4);
  int*  bsum   = (int*)alloc(SCB * 4);
  float* invd  = (float*)alloc((size_t)NN * 4);
  float* statsb01 = (float*)alloc((size_t)2 * SREP * 256 * 4);  // 128 KB
  float* statsb0 = statsb01;
  float* statsb1 = statsb01 + SREP * 256;

  const int EB = (EE + 255) / 256;
  const int GEMMB = (NN + 63) / 64;  // 782

  // ---- prep
  hipMemsetAsync(cnts, 0, (size_t)NN * 2 * 4, stream);
  hipMemsetAsync(agg, 0, AGG_B, stream);
  hipMemsetAsync(statsb01, 0, (size_t)2 * SREP * 256 * 4, stream);
  count2_k<<<EB, 256, 0, stream>>>(ei, cnt_s, cnt_d);
  wpk_k<<<320, 256, 0, stream>>>(Wl0, Wr0, Wl1, Wr1, Wl2, Wr2, wbuf);
  scanA_k<<<SCB, 256, 0, stream>>>(cnt_s, cur_s, bsum);
  scanB_k<<<1, 64, 0, stream>>>(bsum);
  scanC_k<<<SCB, 256, 0, stream>>>(cur_s, bsum, cnt_d, invd);
  fill_csc_k<<<EB, 256, 0, stream>>>(ei, ew, cur_s, e4);

  const int EG128 = (int)(((size_t)EE * 64 + 255) / 256);
  const int EG64  = (int)(((size_t)EE * 32 + 255) / 256);

  // ---- layer 0 (H = x f32, no BN)
  gemm_tl<128, false, false><<<GEMMB, 256, 0, stream>>>(x, wbuf, nullptr, nullptr, nullptr, tlb);
  edge_atomic<128><<<EG128, 256, 0, stream>>>(tlb, e4, agg);
  combine_gemm<128, false, false, true, true, false><<<GEMMB, 256, 0, stream>>>(
      x, wbuf + 16384, nullptr, nullptr, nullptr, agg, invd, b0, hpreA, statsb0);

  // ---- layer 1 (H = hpreA bf16, BN0 inline from statsb0)
  gemm_tl<128, true, true><<<GEMMB, 256, 0, stream>>>(hpreA, wbuf + 32768, statsb0, g0, be0, tlb);
  edge_atomic<128><<<EG128, 256, 0, stream>>>(tlb, e4, agg);
  combine_gemm<128, true, true, true, true, false><<<GEMMB, 256, 0, stream>>>(
      hpreA, wbuf + 49152, statsb0, g0, be0, agg, invd, b1, hpreB, statsb1);

  // ---- layer 2 (H = hpreB bf16, BN1 inline from statsb1; out f32)
  gemm_tl<64, true, true><<<GEMMB, 256, 0, stream>>>(hpreB, wbuf + 65536, statsb1, g1, be1, tlb);
  edge_atomic<64><<<EG64, 256, 0, stream>>>(tlb, e4, agg);
  combine_gemm<64, true, true, false, false, true><<<GEMMB, 256, 0, stream>>>(
      hpreB, wbuf + 73728, statsb1, g1, be1, agg, invd, b2, out, nullptr);
}

// Round 14
// 615.515 us; speedup vs baseline: 1.0964x; 1.0964x over previous
//
#include <hip/hip_runtime.h>
#include <hip/hip_bf16.h>

#define NN 50000
#define EE 600000
#define SREP 64   // stats replicas (atomic decontention)
#define SCB 49    // scan blocks: 49 x 1024 elems >= NN

#if __has_builtin(__builtin_amdgcn_global_atomic_fadd_v2bf16)
#define USE_PK 1
typedef short bf2v __attribute__((ext_vector_type(2)));
#else
#define USE_PK 0
#endif

typedef short bf16x8 __attribute__((ext_vector_type(8)));
typedef float f32x4 __attribute__((ext_vector_type(4)));

__device__ inline ushort f2bf(float x) {  // round-to-nearest-even bf16
  unsigned u = __float_as_uint(x);
  u = (u + 0x7fffu + ((u >> 16) & 1u)) >> 16;
  return (ushort)u;
}
__device__ inline float bflo(uint t) { return __uint_as_float(t << 16); }
__device__ inline float bfhi(uint t) { return __uint_as_float(t & 0xffff0000u); }
__device__ inline uint f22bf(float a, float b) { return ((uint)f2bf(b) << 16) | (uint)f2bf(a); }

// ---------- graph preprocessing ----------
__global__ void count2_k(const int* __restrict__ ei, int* __restrict__ cnt_s,
                         int* __restrict__ cnt_d) {
  int e = blockIdx.x * 256 + threadIdx.x;
  if (e < EE) {
    atomicAdd(&cnt_s[ei[e]], 1);
    atomicAdd(&cnt_d[ei[EE + e]], 1);
  }
}

__global__ __launch_bounds__(256) void scanA_k(const int* __restrict__ cnt,
                                               int* __restrict__ cur,
                                               int* __restrict__ bsum) {
  __shared__ int ls[256];
  const int t = threadIdx.x;
  const int base = blockIdx.x * 1024 + t * 4;
  int4 v = {0, 0, 0, 0};
  if (base + 3 < NN) v = *(const int4*)(cnt + base);
  else {
    if (base + 0 < NN) v.x = cnt[base + 0];
    if (base + 1 < NN) v.y = cnt[base + 1];
    if (base + 2 < NN) v.z = cnt[base + 2];
  }
  ls[t] = v.x + v.y + v.z + v.w;
  __syncthreads();
  for (int off = 1; off < 256; off <<= 1) {
    int u = (t >= off) ? ls[t - off] : 0;
    __syncthreads();
    ls[t] += u;
    __syncthreads();
  }
  int ex = (t == 0) ? 0 : ls[t - 1];
  int4 o;
  o.x = ex;
  o.y = ex + v.x;
  o.z = o.y + v.y;
  o.w = o.z + v.z;
  if (base + 3 < NN) *(int4*)(cur + base) = o;
  else {
    if (base + 0 < NN) cur[base + 0] = o.x;
    if (base + 1 < NN) cur[base + 1] = o.y;
    if (base + 2 < NN) cur[base + 2] = o.z;
  }
  if (t == 255) bsum[blockIdx.x] = ls[255];
}

__global__ __launch_bounds__(64) void scanB_k(int* __restrict__ bsum) {
  int t = threadIdx.x;
  int own = (t < SCB) ? bsum[t] : 0;
  int v = own;
#pragma unroll
  for (int off = 1; off < 64; off <<= 1) {
    int u = __shfl_up(v, off, 64);
    if (t >= off) v += u;
  }
  if (t < SCB) bsum[t] = v - own;
}

__global__ __launch_bounds__(256) void scanC_k(int* __restrict__ cur,
                                               const int* __restrict__ bsum,
                                               const int* __restrict__ cnt_d,
                                               float* __restrict__ invd) {
  const int t = threadIdx.x;
  const int base = blockIdx.x * 1024 + t * 4;
  const int off = bsum[blockIdx.x];
  if (base + 3 < NN) {
    int4 v = *(int4*)(cur + base);
    v.x += off; v.y += off; v.z += off; v.w += off;
    *(int4*)(cur + base) = v;
    int4 cd = *(const int4*)(cnt_d + base);
    float4 iv;
    iv.x = 1.0f / (float)max(cd.x, 1);
    iv.y = 1.0f / (float)max(cd.y, 1);
    iv.z = 1.0f / (float)max(cd.z, 1);
    iv.w = 1.0f / (float)max(cd.w, 1);
    *(float4*)(invd + base) = iv;
  } else {
    for (int i = 0; i < 4; ++i) {
      if (base + i < NN) {
        cur[base + i] += off;
        invd[base + i] = 1.0f / (float)max(cnt_d[base + i], 1);
      }
    }
  }
}

__global__ void fill_csc_k(const int* __restrict__ ei, const float* __restrict__ ew,
                           int* __restrict__ cur_s, int4* __restrict__ e4) {
  int e = blockIdx.x * 256 + threadIdx.x;
  if (e < EE) {
    int s = ei[e], d = ei[EE + e];
    int pc = atomicAdd(&cur_s[s], 1);
    int4 v;
    v.x = s; v.y = d; v.z = __float_as_int(ew[e]); v.w = 0;
    e4[pc] = v;
  }
}

// ---------- weight precompute: all 6 W matrices -> bf16 swizzled image ----
__global__ void wpk_k(const float* __restrict__ Wl0, const float* __restrict__ Wr0,
                      const float* __restrict__ Wl1, const float* __restrict__ Wr1,
                      const float* __restrict__ Wl2, const float* __restrict__ Wr2,
                      ushort* __restrict__ wbuf) {
  int idx = blockIdx.x * 256 + threadIdx.x;  // 0..81919
  const float* W; int F, r, off;
  if (idx < 16384)      { W = Wl0; F = 128; r = idx;         off = 0; }
  else if (idx < 32768) { W = Wr0; F = 128; r = idx - 16384; off = 16384; }
  else if (idx < 49152) { W = Wl1; F = 128; r = idx - 32768; off = 32768; }
  else if (idx < 65536) { W = Wr1; F = 128; r = idx - 49152; off = 49152; }
  else if (idx < 73728) { W = Wl2; F = 64;  r = idx - 65536; off = 65536; }
  else                  { W = Wr2; F = 64;  r = idx - 73728; off = 73728; }
  int k = r / F, n = r % F;
  wbuf[off + n * 128 + ((((k >> 3) + n) & 15) << 3) + (k & 7)] = f2bf(W[k * F + n]);
}

// ---------- MFMA dual GEMM: Tlb = bnrelu(H)@Wl (bf16 chunked), Trb = ..@Wr ----
// HB16: H is bf16 [n][128] with BN(ss)+relu; else H is f32, no BN.
template <int F, bool HB16>
__global__ __launch_bounds__(256) void gemm_mfma(
    const void* __restrict__ H, const ushort* __restrict__ Wpre,
    const float* __restrict__ ss, ushort* __restrict__ Tlb,
    ushort* __restrict__ Trb) {
  __shared__ __align__(16) ushort Wt[F * 128];
  __shared__ __align__(16) ushort Hs[64 * 128];
  const int tid = threadIdx.x;
  const int nb = blockIdx.x * 64;

  if (HB16) {
    for (int i = tid; i < 64 * 16; i += 256) {
      int m = i >> 4, c = i & 15;
      int node = nb + m;
      uint4 hv = {0, 0, 0, 0};
      if (node < NN) hv = ((const uint4*)H)[(size_t)node * 16 + c];
      int gk = c * 8;
      uint* p = (uint*)&hv;
#pragma unroll
      for (int j = 0; j < 4; ++j) {
        float f0 = fmaxf(fmaf(bflo(p[j]), ss[gk + 2 * j], ss[128 + gk + 2 * j]), 0.f);
        float f1 = fmaxf(fmaf(bfhi(p[j]), ss[gk + 2 * j + 1], ss[128 + gk + 2 * j + 1]), 0.f);
        p[j] = f22bf(f0, f1);
      }
      *(uint4*)&Hs[m * 128 + (((c + m) & 15) << 3)] = hv;
    }
  } else {
    for (int i = tid; i < 64 * 32; i += 256) {
      int m = i >> 5, kq = i & 31;
      int node = nb + m;
      float4 hv = {0.f, 0.f, 0.f, 0.f};
      if (node < NN) hv = ((const float4*)H)[(size_t)node * 32 + kq];
      int c = kq >> 1;
      int base = m * 128 + (((c + m) & 15) << 3) + (kq & 1) * 4;
      ushort4 u4 = {f2bf(hv.x), f2bf(hv.y), f2bf(hv.z), f2bf(hv.w)};
      *(ushort4*)&Hs[base] = u4;
    }
  }
  __syncthreads();

  const int lane = tid & 63;
  const int w = tid >> 6;
  const int col = lane & 15;
  const int quad = lane >> 4;
  const int m = w * 16 + col;

  bf16x8 afrag[4];
#pragma unroll
  for (int s = 0; s < 4; ++s) {
    int c = s * 4 + quad;
    afrag[s] = *(const bf16x8*)&Hs[m * 128 + (((c + m) & 15) << 3)];
  }

  for (int phase = 0; phase < 2; ++phase) {
    const uint4* src = (const uint4*)(Wpre + phase * F * 128);
    __syncthreads();
    for (int i = tid; i < F * 16; i += 256) ((uint4*)Wt)[i] = src[i];
    __syncthreads();
#pragma unroll 2
    for (int ct = 0; ct < F / 16; ++ct) {
      int n = ct * 16 + col;
      f32x4 acc = {0.f, 0.f, 0.f, 0.f};
#pragma unroll
      for (int s = 0; s < 4; ++s) {
        int c = s * 4 + quad;
        bf16x8 b = *(const bf16x8*)&Wt[n * 128 + (((c + n) & 15) << 3)];
        acc = __builtin_amdgcn_mfma_f32_16x16x32_bf16(afrag[s], b, acc, 0, 0, 0);
      }
      int nodeb = nb + w * 16 + quad * 4;
#pragma unroll
      for (int r = 0; r < 4; ++r) {
        int node = nodeb + r;
        if (node < NN) {
          int cc = ct * 16 + col;
          if (phase == 0) {
            Tlb[(size_t)(cc >> 5) * NN * 32 + (size_t)node * 32 + (cc & 31)] = f2bf(acc[r]);
          } else {
            Trb[(size_t)node * F + cc] = f2bf(acc[r]);
          }
        }
      }
    }
  }
}

// ---------- edge-parallel aggregation via HW pk-bf16 atomics ----------
// At the measured atomic roofline (~0.94 RMW/clk/slice) — structural floor.
template <int F>
__global__ __launch_bounds__(256, 8) void edge_atomic(
    const ushort* __restrict__ Tlb, const int4* __restrict__ e4,
    void* __restrict__ agg) {
  constexpr int L = F / 2;
  int gid = blockIdx.x * 256 + threadIdx.x;
  int e = gid / L;
  int cp = gid % L;
  if (e >= EE) return;
  int4 p = e4[e];
  float w = __int_as_float(p.z);
  int chunk = cp >> 4, coff = cp & 15;
  uint t = ((const uint*)Tlb)[(size_t)chunk * NN * 16 + (size_t)p.x * 16 + coff];
  float f0 = w * bflo(t);
  float f1 = w * bfhi(t);
#if USE_PK
  bf2v v;
  v.x = (short)f2bf(f0);
  v.y = (short)f2bf(f1);
  __builtin_amdgcn_global_atomic_fadd_v2bf16((bf2v*)((char*)agg + ((size_t)p.y * L + cp) * 4), v);
#else
  float* a = (float*)agg + ((size_t)p.y * L + cp) * 2;
  atomicAdd(a, f0);
  atomicAdd(a + 1, f1);
#endif
}

// ---------- combine: out = agg*invd + Trb + bias (+BN stats; zero agg) ----
// OUTF32: write f32 (final layer to d_out); else pack bf16 (hpre).
template <int F, bool STATS, bool ZERO, bool OUTF32>
__global__ __launch_bounds__(256, 8) void combine(
    void* __restrict__ agg, const ushort* __restrict__ Trb,
    const float* __restrict__ invd, const float* __restrict__ bias,
    void* __restrict__ outp, float* __restrict__ statsb) {
  constexpr int L = F / 2;
  constexpr int NPI = 256 / L;
  constexpr int NPB = 40;  // 50000/40 = 1250 blocks exact
  const int tid = threadIdx.x;
  const int cp = tid % L;
  const int c = 2 * cp;
  const int nl = tid / L;
  const int n0 = blockIdx.x * NPB;
  const float bx = bias[c], by = bias[c + 1];
  float2 S = {0.f, 0.f}, Q = {0.f, 0.f};
#pragma unroll
  for (int it = 0; it < NPB / NPI; ++it) {
    int n = n0 + it * NPI + nl;
    float a0, a1;
#if USE_PK
    uint t = ((uint*)agg)[(size_t)n * L + cp];
    a0 = bflo(t);
    a1 = bfhi(t);
    if (ZERO) ((uint*)agg)[(size_t)n * L + cp] = 0;
#else
    float2 af = ((float2*)agg)[(size_t)n * L + cp];
    a0 = af.x;
    a1 = af.y;
    if (ZERO) { float2 z = {0.f, 0.f}; ((float2*)agg)[(size_t)n * L + cp] = z; }
#endif
    float iv = invd[n];
    uint tb = ((const uint*)Trb)[(size_t)n * L + cp];
    float2 v;
    v.x = fmaf(a0, iv, bflo(tb) + bx);
    v.y = fmaf(a1, iv, bfhi(tb) + by);
    if (OUTF32) *(float2*)((float*)outp + (size_t)n * F + c) = v;
    else ((uint*)outp)[(size_t)n * L + cp] = f22bf(v.x, v.y);
    if constexpr (STATS) {
      S.x += v.x; S.y += v.y;
      Q.x += v.x * v.x; Q.y += v.y * v.y;
    }
  }
  if constexpr (STATS) {
    __shared__ float2 sS[4][L];
    __shared__ float2 sQ[4][L];
    const int wid = tid >> 6, wl = tid & 63;
    if constexpr (L == 64) {
      sS[wid][wl] = S;
      sQ[wid][wl] = Q;
    } else {
      S.x += __shfl_xor(S.x, 32, 64); S.y += __shfl_xor(S.y, 32, 64);
      Q.x += __shfl_xor(Q.x, 32, 64); Q.y += __shfl_xor(Q.y, 32, 64);
      if (wl < 32) { sS[wid][wl] = S; sQ[wid][wl] = Q; }
    }
    __syncthreads();
    if (tid < L) {
      float2 Sa = sS[0][tid], Qa = sQ[0][tid];
#pragma unroll
      for (int w2 = 1; w2 < 4; ++w2) {
        Sa.x += sS[w2][tid].x; Sa.y += sS[w2][tid].y;
        Qa.x += sQ[w2][tid].x; Qa.y += sQ[w2][tid].y;
      }
      float* sb = statsb + (size_t)(blockIdx.x & (SREP - 1)) * 256;
      int col = 2 * tid;
      atomicAdd(&sb[col], Sa.x);
      atomicAdd(&sb[col + 1], Sa.y);
      atomicAdd(&sb[128 + col], Qa.x);
      atomicAdd(&sb[128 + col + 1], Qa.y);
    }
  }
}

// ---------- BN finalize: reduce SREP replicas, then zero them ----------
__global__ void bn_fin(float* __restrict__ statsb, const float* __restrict__ gamma,
                       const float* __restrict__ beta, float* __restrict__ ss) {
  int f = threadIdx.x;
  float sum = 0.f, sq = 0.f;
#pragma unroll 8
  for (int r = 0; r < SREP; ++r) {
    sum += statsb[r * 256 + f];
    sq  += statsb[r * 256 + 128 + f];
    statsb[r * 256 + f] = 0.f;
    statsb[r * 256 + 128 + f] = 0.f;
  }
  float mu = sum * (1.0f / (float)NN);
  float ex2 = sq * (1.0f / (float)NN);
  float var = ex2 - mu * mu;
  float sc = gamma[f] * rsqrtf(var + 1e-5f);
  ss[f] = sc;
  ss[128 + f] = beta[f] - mu * sc;
}

extern "C" void kernel_launch(void* const* d_in, const int* in_sizes, int n_in,
                              void* d_out, int out_size, void* d_ws, size_t ws_size,
                              hipStream_t stream) {
  (void)in_sizes; (void)n_in; (void)out_size; (void)ws_size;
  const float* x   = (const float*)d_in[0];
  const int*   ei  = (const int*)d_in[1];
  const float* ew  = (const float*)d_in[2];
  const float* Wl0 = (const float*)d_in[3];
  const float* Wr0 = (const float*)d_in[4];
  const float* b0  = (const float*)d_in[5];
  const float* Wl1 = (const float*)d_in[6];
  const float* Wr1 = (const float*)d_in[7];
  const float* b1  = (const float*)d_in[8];
  const float* Wl2 = (const float*)d_in[9];
  const float* Wr2 = (const float*)d_in[10];
  const float* b2  = (const float*)d_in[11];
  const float* g0  = (const float*)d_in[12];
  const float* be0 = (const float*)d_in[13];
  const float* g1  = (const float*)d_in[14];
  const float* be1 = (const float*)d_in[15];
  float* out = (float*)d_out;

  size_t off = 0;
  auto alloc = [&](size_t b) -> void* {
    void* p = (char*)d_ws + off;
    off += (b + 255) & ~(size_t)255;
    return p;
  };
  ushort* tlb  = (ushort*)alloc((size_t)NN * 128 * 2);  // 12.8 MB
  ushort* trb  = (ushort*)alloc((size_t)NN * 128 * 2);  // 12.8 MB
  ushort* hpre = (ushort*)alloc((size_t)NN * 128 * 2);  // 12.8 MB (bf16)
#if USE_PK
  const size_t AGG_B = (size_t)NN * 128 * 2;
#else
  const size_t AGG_B = (size_t)NN * 128 * 4;
#endif
  void* agg    = alloc((size_t)NN * 128 * 4);           // 25.6 MB
  int4* e4     = (int4*)alloc((size_t)EE * 16);         // 9.6 MB
  ushort* wbuf = (ushort*)alloc(81920 * 2);             // 160 KB
  int*  cnts   = (int*)alloc((size_t)NN * 2 * 4);
  int*  cnt_s  = cnts;
  int*  cnt_d  = cnts + NN;
  int*  cur_s  = (int*)alloc((size_t)NN * 4);
  int*  bsum   = (int*)alloc(SCB * 4);
  float* invd  = (float*)alloc((size_t)NN * 4);
  float* statsb = (float*)alloc((size_t)SREP * 256 * 4);
  float* ssb   = (float*)alloc(256 * 4);

  const int EB = (EE + 255) / 256;
  const int GEMMB = (NN + 63) / 64;  // 782

  // ---- prep
  hipMemsetAsync(cnts, 0, (size_t)NN * 2 * 4, stream);
  hipMemsetAsync(agg, 0, AGG_B, stream);
  hipMemsetAsync(statsb, 0, (size_t)SREP * 256 * 4, stream);
  count2_k<<<EB, 256, 0, stream>>>(ei, cnt_s, cnt_d);
  wpk_k<<<320, 256, 0, stream>>>(Wl0, Wr0, Wl1, Wr1, Wl2, Wr2, wbuf);
  scanA_k<<<SCB, 256, 0, stream>>>(cnt_s, cur_s, bsum);
  scanB_k<<<1, 64, 0, stream>>>(bsum);
  scanC_k<<<SCB, 256, 0, stream>>>(cur_s, bsum, cnt_d, invd);
  fill_csc_k<<<EB, 256, 0, stream>>>(ei, ew, cur_s, e4);

  const int EG128 = (int)(((size_t)EE * 64 + 255) / 256);
  const int EG64  = (int)(((size_t)EE * 32 + 255) / 256);

  // ---- layer 0 (H = x f32, no BN)
  gemm_mfma<128, false><<<GEMMB, 256, 0, stream>>>(x, wbuf, nullptr, tlb, trb);
  edge_atomic<128><<<EG128, 256, 0, stream>>>(tlb, e4, agg);
  combine<128, true, true, false><<<NN / 40, 256, 0, stream>>>(agg, trb, invd, b0, hpre, statsb);
  bn_fin<<<1, 128, 0, stream>>>(statsb, g0, be0, ssb);

  // ---- layer 1 (H = hpre bf16, BN0+ReLU in staging; agg pre-zeroed by combine)
  gemm_mfma<128, true><<<GEMMB, 256, 0, stream>>>(hpre, wbuf + 32768, ssb, tlb, trb);
  edge_atomic<128><<<EG128, 256, 0, stream>>>(tlb, e4, agg);
  combine<128, true, true, false><<<NN / 40, 256, 0, stream>>>(agg, trb, invd, b1, hpre, statsb);
  bn_fin<<<1, 128, 0, stream>>>(statsb, g1, be1, ssb);

  // ---- layer 2 (H = hpre bf16, BN1+ReLU in staging; out f32 to d_out)
  gemm_mfma<64, true><<<GEMMB, 256, 0, stream>>>(hpre, wbuf + 65536, ssb, tlb, trb);
  edge_atomic<64><<<EG64, 256, 0, stream>>>(tlb, e4, agg);
  combine<64, false, false, true><<<NN / 40, 256, 0, stream>>>(agg, trb, invd, b2, out, nullptr);
}